// Round 10
// baseline (39.110 us; speedup 1.0000x reference)
//
#include <hip/hip_runtime.h>

#define NCLS 7

// ws layout (4-byte slots):
//   [2] float pos_num   [3] float neg_num     (written by main block 0)
//   [16..] per-row partials: float2 (pos, neg)
struct Hdr {
    int   anchor;
    int   a_cls;
    float pos_num;
    float neg_num;
    float inv_at;
    float inv_av;
    float inv_aa;
    int   pad;
};

__device__ __forceinline__ float dot4(float4 a, float4 b) {
    return a.x * b.x + a.y * b.y + a.z * b.z + a.w * b.w;
}

// ---- Wave64 reductions on the VALU pipe via DPP (no DS ops) ---------------
__device__ __forceinline__ float wave_fsum_dpp(float x) {
    float t;
    t = __int_as_float(__builtin_amdgcn_update_dpp(0, __float_as_int(x), 0x111, 0xf, 0xf, true));  x += t;
    t = __int_as_float(__builtin_amdgcn_update_dpp(0, __float_as_int(x), 0x112, 0xf, 0xf, true));  x += t;
    t = __int_as_float(__builtin_amdgcn_update_dpp(0, __float_as_int(x), 0x114, 0xf, 0xf, true));  x += t;
    t = __int_as_float(__builtin_amdgcn_update_dpp(0, __float_as_int(x), 0x118, 0xf, 0xf, true));  x += t;
    t = __int_as_float(__builtin_amdgcn_update_dpp(0, __float_as_int(x), 0x142, 0xa, 0xf, false)); x += t;
    t = __int_as_float(__builtin_amdgcn_update_dpp(0, __float_as_int(x), 0x143, 0xc, 0xf, false)); x += t;
    return __int_as_float(__builtin_amdgcn_readlane(__float_as_int(x), 63));
}

__device__ __forceinline__ int wave_isum_dpp(int x) {
    int t;
    t = __builtin_amdgcn_update_dpp(0, x, 0x111, 0xf, 0xf, true);  x += t;
    t = __builtin_amdgcn_update_dpp(0, x, 0x112, 0xf, 0xf, true);  x += t;
    t = __builtin_amdgcn_update_dpp(0, x, 0x114, 0xf, 0xf, true);  x += t;
    t = __builtin_amdgcn_update_dpp(0, x, 0x118, 0xf, 0xf, true);  x += t;
    t = __builtin_amdgcn_update_dpp(0, x, 0x142, 0xa, 0xf, false); x += t;
    t = __builtin_amdgcn_update_dpp(0, x, 0x143, 0xc, 0xf, false); x += t;
    return __builtin_amdgcn_readlane(x, 63);
}

__device__ __forceinline__ int wave_imin_dpp(int x) {
    const int I = 0x7fffffff;
    int t;
    t = __builtin_amdgcn_update_dpp(I, x, 0x111, 0xf, 0xf, false); x = min(x, t);
    t = __builtin_amdgcn_update_dpp(I, x, 0x112, 0xf, 0xf, false); x = min(x, t);
    t = __builtin_amdgcn_update_dpp(I, x, 0x114, 0xf, 0xf, false); x = min(x, t);
    t = __builtin_amdgcn_update_dpp(I, x, 0x118, 0xf, 0xf, false); x = min(x, t);
    t = __builtin_amdgcn_update_dpp(I, x, 0x142, 0xa, 0xf, false); x = min(x, t);
    t = __builtin_amdgcn_update_dpp(I, x, 0x143, 0xc, 0xf, false); x = min(x, t);
    return __builtin_amdgcn_readlane(x, 63);
}

// ---------------------------------------------------------------------------
// Kernel B (now kernel 1 of 2): prep fused in.
// Phase 0: issue the wave's ENTIRE own-row HBM traffic (12 float4) up front.
// Phase 1: block-local label histogram (registers + DPP + tiny LDS combine)
//          -> a_cls / anchor / pos_num. Overlaps phase-0 load returns; labels
//          are L3-hot after the first blocks. Block 0 publishes pos/neg_num.
// Phase 2: load anchor rows (L2-hot after warmup), 12 dot accumulators
//          (9 cross/own + 3 anchor sumsq -- anchor norms come FREE from
//          registers already loaded, killing prep's 2nd memory phase),
//          7 DPP reductions, lane 0 writes the row's (pos,neg) partial.
// ---------------------------------------------------------------------------
__global__ __launch_bounds__(256, 4) void main_kernel(
    const int* __restrict__ label,
    const float* __restrict__ s_t,
    const float* __restrict__ s_v,
    const float* __restrict__ s_a,
    int B, int D, float* __restrict__ ws)
{
    float2* partials = (float2*)(ws + 16);

    const int tid  = threadIdx.x;
    const int w    = tid >> 6;
    const int lane = tid & 63;
    const int r    = blockIdx.x * 4 + w;          // wave id == row

    const int nvec = D >> 2;
    const bool fast = (nvec == 256) && (r < B);

    const float4* rt = (const float4*)(s_t + (size_t)r * D);
    const float4* rv = (const float4*)(s_v + (size_t)r * D);
    const float4* ra = (const float4*)(s_a + (size_t)r * D);

    // ---- Phase 0: own-row loads first (the wave's full HBM traffic) ----
    float4 T[4], V[4], A[4];
    if (fast) {
#pragma unroll
        for (int it = 0; it < 4; ++it) {
            const int j = lane + (it << 6);
            T[it] = rt[j];  V[it] = rv[j];  A[it] = ra[j];
        }
    }
    const int lab = (r < B) ? label[r] : 0;

    // ---- Phase 1: block histogram (hidden under phase-0 returns) ----
    int cnt[NCLS], mn[NCLS];
#pragma unroll
    for (int k = 0; k < NCLS; ++k) { cnt[k] = 0; mn[k] = 0x7fffffff; }

    const int4* lab4 = (const int4*)label;
    const int n4 = B >> 2;
    for (int j = tid; j < n4; j += 256) {
        int4 L = lab4[j];
        const int base = j << 2;
        int ls[4] = { L.x, L.y, L.z, L.w };
#pragma unroll
        for (int e = 0; e < 4; ++e) {
#pragma unroll
            for (int k = 0; k < NCLS; ++k)
                if (ls[e] == k) { cnt[k]++; mn[k] = min(mn[k], base + e); }
        }
    }
    for (int i = (n4 << 2) + tid; i < B; i += 256) {
        int l = label[i];
#pragma unroll
        for (int k = 0; k < NCLS; ++k)
            if (l == k) { cnt[k]++; mn[k] = min(mn[k], i); }
    }

#pragma unroll
    for (int k = 0; k < NCLS; ++k) {
        cnt[k] = wave_isum_dpp(cnt[k]);
        mn[k]  = wave_imin_dpp(mn[k]);
    }

    __shared__ int s_cnt[4][NCLS], s_mn[4][NCLS];
    if (lane == 0) {
#pragma unroll
        for (int k = 0; k < NCLS; ++k) { s_cnt[w][k] = cnt[k]; s_mn[w][k] = mn[k]; }
    }
    __syncthreads();

    // every thread computes the (identical) anchor metadata from LDS broadcast
    int c = 0;
#pragma unroll
    for (int k = NCLS - 1; k >= 0; --k) {
        int hc = s_cnt[0][k] + s_cnt[1][k] + s_cnt[2][k] + s_cnt[3][k];
        if (hc > 1) c = k;                 // first class with count>1, else 0
    }
    const int acls   = c;
    const int posn   = s_cnt[0][c] + s_cnt[1][c] + s_cnt[2][c] + s_cnt[3][c];
    const int anchor = min(min(s_mn[0][c], s_mn[1][c]), min(s_mn[2][c], s_mn[3][c]));

    if (blockIdx.x == 0 && tid == 0) {
        ws[2] = (float)posn;               // pos_num
        ws[3] = (float)(B - posn);         // neg_num
    }
    if (r >= B) return;                    // no further barriers below

    // ---- Phase 2: anchor loads (L2-hot) + compute ----
    const float4* at = (const float4*)(s_t + (size_t)anchor * D);
    const float4* av = (const float4*)(s_v + (size_t)anchor * D);
    const float4* aa = (const float4*)(s_a + (size_t)anchor * D);

    float dt_a = 0.f, dt_v = 0.f, sq_t = 0.f;
    float dv_t = 0.f, dv_a = 0.f, sq_v = 0.f;
    float da_t = 0.f, da_v = 0.f, sq_a = 0.f;
    float qa_t = 0.f, qa_v = 0.f, qa_a = 0.f;   // anchor sumsq (free, from regs)

    if (fast) {
#pragma unroll
        for (int it = 0; it < 4; ++it) {
            const int j = lane + (it << 6);
            float4 bt = at[j], bv = av[j], ba = aa[j];
            dt_a += dot4(T[it], ba);  dt_v += dot4(T[it], bv);  sq_t += dot4(T[it], T[it]);
            dv_t += dot4(V[it], bt);  dv_a += dot4(V[it], ba);  sq_v += dot4(V[it], V[it]);
            da_t += dot4(A[it], bt);  da_v += dot4(A[it], bv);  sq_a += dot4(A[it], A[it]);
            qa_t += dot4(bt, bt);     qa_v += dot4(bv, bv);     qa_a += dot4(ba, ba);
        }
    } else {
#pragma unroll 1
        for (int j = lane; j < nvec; j += 64) {
            float4 t  = rt[j], v  = rv[j], a  = ra[j];
            float4 bt = at[j], bv = av[j], ba = aa[j];
            dt_a += dot4(t, ba);  dt_v += dot4(t, bv);  sq_t += dot4(t, t);
            dv_t += dot4(v, bt);  dv_a += dot4(v, ba);  sq_v += dot4(v, v);
            da_t += dot4(a, bt);  da_v += dot4(a, bv);  sq_a += dot4(a, a);
            qa_t += dot4(bt, bt); qa_v += dot4(bv, bv); qa_a += dot4(ba, ba);
        }
    }

    const float inv_t  = rsqrtf(wave_fsum_dpp(sq_t));
    const float inv_v  = rsqrtf(wave_fsum_dpp(sq_v));
    const float inv_a  = rsqrtf(wave_fsum_dpp(sq_a));
    const float inv_at = rsqrtf(wave_fsum_dpp(qa_t));
    const float inv_av = rsqrtf(wave_fsum_dpp(qa_v));
    const float inv_aa = rsqrtf(wave_fsum_dpp(qa_a));

    float cc = inv_t * (dt_a * inv_aa + dt_v * inv_av)
             + inv_v * (dv_t * inv_at + dv_a * inv_aa)
             + inv_a * (da_t * inv_at + da_v * inv_av);
    const float rowtot = wave_fsum_dpp(cc);

    if (lane == 0) {
        bool isPos = (lab == acls) && (r != anchor);
        bool isNeg = (lab != acls);
        partials[r] = make_float2(isPos ? rowtot : 0.f, isNeg ? rowtot : 0.f);
    }
}

// ---------------------------------------------------------------------------
// Kernel C: deterministic reduction of B partial pairs -> scalar loss.
// loss = (6 - pos_total/pos_num + neg_total/neg_num) / 3
// ---------------------------------------------------------------------------
__global__ __launch_bounds__(1024) void finish_kernel(
    const float* __restrict__ ws, int B, float* __restrict__ out)
{
    const Hdr* h = (const Hdr*)ws;
    const float4* p4 = (const float4*)(ws + 16);   // (pos,neg,pos,neg)

    float p = 0.f, n = 0.f;
    const int n4 = B >> 1;                         // float4 count (B even)
    for (int j = threadIdx.x; j < n4; j += 1024) {
        float4 x = p4[j];
        p += x.x + x.z;
        n += x.y + x.w;
    }
    p = wave_fsum_dpp(p);
    n = wave_fsum_dpp(n);

    __shared__ float pp[16], nn[16];
    const int w = threadIdx.x >> 6, lane = threadIdx.x & 63;
    if (lane == 0) { pp[w] = p; nn[w] = n; }
    __syncthreads();
    if (threadIdx.x == 0) {
        float P = 0.f, N = 0.f;
#pragma unroll
        for (int k = 0; k < 16; ++k) { P += pp[k]; N += nn[k]; }
        out[0] = (6.0f - P / h->pos_num + N / h->neg_num) / 3.0f;
    }
}

extern "C" void kernel_launch(void* const* d_in, const int* in_sizes, int n_in,
                              void* d_out, int out_size, void* d_ws, size_t ws_size,
                              hipStream_t stream) {
    const int*   label = (const int*)d_in[0];
    const float* s_t   = (const float*)d_in[1];
    const float* s_v   = (const float*)d_in[2];
    const float* s_a   = (const float*)d_in[3];

    const int B = in_sizes[0];
    const int D = in_sizes[1] / B;   // 1024

    float* ws  = (float*)d_ws;
    float* out = (float*)d_out;

    const int nblocks = (B + 3) / 4;   // one wave per row, 4 waves per block

    main_kernel<<<nblocks, 256, 0, stream>>>(label, s_t, s_v, s_a, B, D, ws);
    finish_kernel<<<1, 1024, 0, stream>>>(ws, B, out);
}

// Round 11
// 31.552 us; speedup vs baseline: 1.2395x; 1.2395x over previous
//
#include <hip/hip_runtime.h>

#define NCLS 7

// ws layout (4-byte slots):
//   [0] int   anchor   [1] int a_cls
//   [2] float pos_num  [3] float neg_num
//   [4..15] pad
//   [16..]  per-row partials: float2 (pos, neg)
struct Hdr {
    int   anchor;
    int   a_cls;
    float pos_num;
    float neg_num;
};

__device__ __forceinline__ float dot4(float4 a, float4 b) {
    return a.x * b.x + a.y * b.y + a.z * b.z + a.w * b.w;
}

// ---- Wave64 reductions on the VALU pipe via DPP (no DS ops) ---------------
__device__ __forceinline__ float wave_fsum_dpp(float x) {
    float t;
    t = __int_as_float(__builtin_amdgcn_update_dpp(0, __float_as_int(x), 0x111, 0xf, 0xf, true));  x += t;
    t = __int_as_float(__builtin_amdgcn_update_dpp(0, __float_as_int(x), 0x112, 0xf, 0xf, true));  x += t;
    t = __int_as_float(__builtin_amdgcn_update_dpp(0, __float_as_int(x), 0x114, 0xf, 0xf, true));  x += t;
    t = __int_as_float(__builtin_amdgcn_update_dpp(0, __float_as_int(x), 0x118, 0xf, 0xf, true));  x += t;
    t = __int_as_float(__builtin_amdgcn_update_dpp(0, __float_as_int(x), 0x142, 0xa, 0xf, false)); x += t;
    t = __int_as_float(__builtin_amdgcn_update_dpp(0, __float_as_int(x), 0x143, 0xc, 0xf, false)); x += t;
    return __int_as_float(__builtin_amdgcn_readlane(__float_as_int(x), 63));
}

__device__ __forceinline__ int wave_isum_dpp(int x) {
    int t;
    t = __builtin_amdgcn_update_dpp(0, x, 0x111, 0xf, 0xf, true);  x += t;
    t = __builtin_amdgcn_update_dpp(0, x, 0x112, 0xf, 0xf, true);  x += t;
    t = __builtin_amdgcn_update_dpp(0, x, 0x114, 0xf, 0xf, true);  x += t;
    t = __builtin_amdgcn_update_dpp(0, x, 0x118, 0xf, 0xf, true);  x += t;
    t = __builtin_amdgcn_update_dpp(0, x, 0x142, 0xa, 0xf, false); x += t;
    t = __builtin_amdgcn_update_dpp(0, x, 0x143, 0xc, 0xf, false); x += t;
    return __builtin_amdgcn_readlane(x, 63);
}

__device__ __forceinline__ int wave_imin_dpp(int x) {
    const int I = 0x7fffffff;
    int t;
    t = __builtin_amdgcn_update_dpp(I, x, 0x111, 0xf, 0xf, false); x = min(x, t);
    t = __builtin_amdgcn_update_dpp(I, x, 0x112, 0xf, 0xf, false); x = min(x, t);
    t = __builtin_amdgcn_update_dpp(I, x, 0x114, 0xf, 0xf, false); x = min(x, t);
    t = __builtin_amdgcn_update_dpp(I, x, 0x118, 0xf, 0xf, false); x = min(x, t);
    t = __builtin_amdgcn_update_dpp(I, x, 0x142, 0xa, 0xf, false); x = min(x, t);
    t = __builtin_amdgcn_update_dpp(I, x, 0x143, 0xc, 0xf, false); x = min(x, t);
    return __builtin_amdgcn_readlane(x, 63);
}

// ---------------------------------------------------------------------------
// Kernel A — LABELS ONLY (r10 post-mortem: the anchor-norm phase moved into
// main, where the anchor rows are loaded anyway; prep loses its second
// dependent memory round-trip). One 32 KB pass, register histogram +
// per-class min index, DPP reduce, header write. ~1.5 us.
// ---------------------------------------------------------------------------
__global__ __launch_bounds__(1024) void prep_kernel(
    const int* __restrict__ label, int B, float* __restrict__ ws)
{
    const int tid  = threadIdx.x;
    const int w    = tid >> 6;
    const int lane = tid & 63;

    int cnt[NCLS], mn[NCLS];
#pragma unroll
    for (int k = 0; k < NCLS; ++k) { cnt[k] = 0; mn[k] = 0x7fffffff; }

    const int4* lab4 = (const int4*)label;
    const int n4 = B >> 2;
    for (int j = tid; j < n4; j += 1024) {
        int4 L = lab4[j];
        const int base = j << 2;
        int ls[4] = { L.x, L.y, L.z, L.w };
#pragma unroll
        for (int e = 0; e < 4; ++e) {
#pragma unroll
            for (int k = 0; k < NCLS; ++k)
                if (ls[e] == k) { cnt[k]++; mn[k] = min(mn[k], base + e); }
        }
    }
    for (int i = (n4 << 2) + tid; i < B; i += 1024) {
        int l = label[i];
#pragma unroll
        for (int k = 0; k < NCLS; ++k)
            if (l == k) { cnt[k]++; mn[k] = min(mn[k], i); }
    }

#pragma unroll
    for (int k = 0; k < NCLS; ++k) {
        cnt[k] = wave_isum_dpp(cnt[k]);
        mn[k]  = wave_imin_dpp(mn[k]);
    }

    __shared__ int s_cnt[16][NCLS], s_mn[16][NCLS];
    if (lane == 0) {
#pragma unroll
        for (int k = 0; k < NCLS; ++k) { s_cnt[w][k] = cnt[k]; s_mn[w][k] = mn[k]; }
    }
    __syncthreads();

    if (tid == 0) {
        int hist[NCLS], mini[NCLS];
#pragma unroll
        for (int k = 0; k < NCLS; ++k) {
            int hc = 0, mc = 0x7fffffff;
            for (int q = 0; q < 16; ++q) { hc += s_cnt[q][k]; mc = min(mc, s_mn[q][k]); }
            hist[k] = hc; mini[k] = mc;
        }
        // jnp.argmax(counts > 1): first class with count>1, else 0
        int c = 0;
#pragma unroll
        for (int k = NCLS - 1; k >= 0; --k) if (hist[k] > 1) c = k;

        int* wi = (int*)ws;
        wi[0] = mini[c];                  // anchor
        wi[1] = c;                        // a_cls
        ws[2] = (float)hist[c];           // pos_num
        ws[3] = (float)(B - hist[c]);     // neg_num
    }
}

// ---------------------------------------------------------------------------
// Kernel B: one wave per row, zero LDS/DS in the hot path, low-VGPR unroll-1
// loop (r9 shape, the fastest measured). Anchor norms computed HERE from the
// anchor registers already loaded for the cross-dots (validated in r10,
// absmax=0): 12 dot accumulators, 7 DPP reductions, identical in every wave
// -> bitwise deterministic.
// ---------------------------------------------------------------------------
__global__ __launch_bounds__(256, 8) void main_kernel(
    const int* __restrict__ label,
    const float* __restrict__ s_t,
    const float* __restrict__ s_v,
    const float* __restrict__ s_a,
    int B, int D, float* __restrict__ ws)
{
    const Hdr* h = (const Hdr*)ws;
    float2* partials = (float2*)(ws + 16);

    const int lane = threadIdx.x & 63;
    const int r    = blockIdx.x * 4 + (threadIdx.x >> 6);   // wave id == row
    if (r >= B) return;

    const int anchor = h->anchor;
    const int acls   = h->a_cls;
    const int lab    = label[r];

    const float4* rt = (const float4*)(s_t + (size_t)r * D);
    const float4* rv = (const float4*)(s_v + (size_t)r * D);
    const float4* ra = (const float4*)(s_a + (size_t)r * D);
    const float4* at = (const float4*)(s_t + (size_t)anchor * D);
    const float4* av = (const float4*)(s_v + (size_t)anchor * D);
    const float4* aa = (const float4*)(s_a + (size_t)anchor * D);

    float dt_a = 0.f, dt_v = 0.f, sq_t = 0.f;
    float dv_t = 0.f, dv_a = 0.f, sq_v = 0.f;
    float da_t = 0.f, da_v = 0.f, sq_a = 0.f;
    float qa_t = 0.f, qa_v = 0.f, qa_a = 0.f;   // anchor sumsq — free (regs)

    const int nvec = D >> 2;
#pragma unroll 1
    for (int j = lane; j < nvec; j += 64) {
        float4 t  = rt[j], v  = rv[j], a  = ra[j];
        float4 bt = at[j], bv = av[j], ba = aa[j];
        dt_a += dot4(t, ba);  dt_v += dot4(t, bv);  sq_t += dot4(t, t);
        dv_t += dot4(v, bt);  dv_a += dot4(v, ba);  sq_v += dot4(v, v);
        da_t += dot4(a, bt);  da_v += dot4(a, bv);  sq_a += dot4(a, a);
        qa_t += dot4(bt, bt); qa_v += dot4(bv, bv); qa_a += dot4(ba, ba);
    }

    const float inv_t  = rsqrtf(wave_fsum_dpp(sq_t));
    const float inv_v  = rsqrtf(wave_fsum_dpp(sq_v));
    const float inv_a  = rsqrtf(wave_fsum_dpp(sq_a));
    const float inv_at = rsqrtf(wave_fsum_dpp(qa_t));
    const float inv_av = rsqrtf(wave_fsum_dpp(qa_v));
    const float inv_aa = rsqrtf(wave_fsum_dpp(qa_a));

    float c = inv_t * (dt_a * inv_aa + dt_v * inv_av)
            + inv_v * (dv_t * inv_at + dv_a * inv_aa)
            + inv_a * (da_t * inv_at + da_v * inv_av);
    const float rowtot = wave_fsum_dpp(c);

    if (lane == 0) {
        bool isPos = (lab == acls) && (r != anchor);
        bool isNeg = (lab != acls);
        partials[r] = make_float2(isPos ? rowtot : 0.f, isNeg ? rowtot : 0.f);
    }
}

// ---------------------------------------------------------------------------
// Kernel C: deterministic reduction of B partial pairs -> scalar loss.
// loss = (6 - pos_total/pos_num + neg_total/neg_num) / 3
// ---------------------------------------------------------------------------
__global__ __launch_bounds__(1024) void finish_kernel(
    const float* __restrict__ ws, int B, float* __restrict__ out)
{
    const Hdr* h = (const Hdr*)ws;
    const float4* p4 = (const float4*)(ws + 16);   // (pos,neg,pos,neg)

    float p = 0.f, n = 0.f;
    const int n4 = B >> 1;                         // float4 count (B even)
    for (int j = threadIdx.x; j < n4; j += 1024) {
        float4 x = p4[j];
        p += x.x + x.z;
        n += x.y + x.w;
    }
    p = wave_fsum_dpp(p);
    n = wave_fsum_dpp(n);

    __shared__ float pp[16], nn[16];
    const int w = threadIdx.x >> 6, lane = threadIdx.x & 63;
    if (lane == 0) { pp[w] = p; nn[w] = n; }
    __syncthreads();
    if (threadIdx.x == 0) {
        float P = 0.f, N = 0.f;
#pragma unroll
        for (int k = 0; k < 16; ++k) { P += pp[k]; N += nn[k]; }
        out[0] = (6.0f - P / h->pos_num + N / h->neg_num) / 3.0f;
    }
}

extern "C" void kernel_launch(void* const* d_in, const int* in_sizes, int n_in,
                              void* d_out, int out_size, void* d_ws, size_t ws_size,
                              hipStream_t stream) {
    const int*   label = (const int*)d_in[0];
    const float* s_t   = (const float*)d_in[1];
    const float* s_v   = (const float*)d_in[2];
    const float* s_a   = (const float*)d_in[3];

    const int B = in_sizes[0];
    const int D = in_sizes[1] / B;   // 1024

    float* ws  = (float*)d_ws;
    float* out = (float*)d_out;

    const int nblocks = (B + 3) / 4;   // one wave per row, 4 waves per block

    prep_kernel<<<1, 1024, 0, stream>>>(label, B, ws);
    main_kernel<<<nblocks, 256, 0, stream>>>(label, s_t, s_v, s_a, B, D, ws);
    finish_kernel<<<1, 1024, 0, stream>>>(ws, B, out);
}